// Round 5
// baseline (221.549 us; speedup 1.0000x reference)
//
#include <hip/hip_runtime.h>
#include <hip/hip_bf16.h>
#include <math.h>

// MultiHeadSelfAttention: x[1,4096,1024] fp32, Wq/Wk/Wv/Wo[1024,1024] fp32 -> out fp32.
// R4: barrier-free attention (kv range split across the 4 waves, one end merge),
// fragments loaded straight global->register from MFMA-tiled layouts, but the
// per-tile compute uses ONLY the R2-proven mfma orientation and Ps round-trip:
//   S = mfma(Q_asA, K_asB): row=q(quad*4+r), col=kv(l15)  [R1/R2-verified]
//   P -> LDS (row=q, col=kv, stride 68) -> A-frag b64-pair reads  [R2-verified]
// R3's unverified transpose-swap + packed-b64 P writes + strip-reuse are removed.
// Explicit s_waitcnt lgkmcnt(0) guards replace the ordering __syncthreads gave R2.
//
// Tiled layouts (per head, 256KB = 4096x64 bf16), hand-verified producer/consumer:
//   Q'/K'[t16 = s>>4][g8 = d>>3][l = s&15][j = d&7]   (granule = 8 bf16 = 16B)
//   V'  [od = d>>4][kg = s>>3][l = d&15][j = s&7]

#define S_LEN 4096
#define DMODEL 1024
#define NHEAD 16
// 0.125 (1/sqrt(64)) * log2(e): folded into Q so attn uses exp2 directly
#define QSCALE 0.1803368801111244f

typedef __attribute__((ext_vector_type(8))) short short8;   // 8 bf16 = 4 VGPRs
typedef __attribute__((ext_vector_type(4))) short short4_t; // 4 bf16 = 2 VGPRs
typedef __attribute__((ext_vector_type(4))) float floatx4;  // MFMA C/D frag

static __device__ __forceinline__ void load_lds16(const void* g, void* l) {
    __builtin_amdgcn_global_load_lds((const __attribute__((address_space(1))) void*)g,
                                     (__attribute__((address_space(3))) void*)l, 16, 0, 0);
}

// one fused launch for all 5 fp32->bf16 conversions
__global__ void cvt_all_kernel(const float* __restrict__ x,  const float* __restrict__ wq,
                               const float* __restrict__ wk, const float* __restrict__ wv,
                               const float* __restrict__ wo,
                               __hip_bfloat16* __restrict__ xb,  __hip_bfloat16* __restrict__ wqb,
                               __hip_bfloat16* __restrict__ wkb, __hip_bfloat16* __restrict__ wvb,
                               __hip_bfloat16* __restrict__ wob)
{
    const size_t NX = (size_t)S_LEN * DMODEL;   // 4M
    const size_t NW = (size_t)DMODEL * DMODEL;  // 1M
    size_t t = ((size_t)blockIdx.x * blockDim.x + threadIdx.x) * 4;
    const float* src; __hip_bfloat16* dst; size_t off;
    if (t < NX) { src = x; dst = xb; off = t; }
    else {
        size_t j = t - NX; int seg = (int)(j >> 20); off = j & (NW - 1);
        src = (seg == 0) ? wq : (seg == 1) ? wk : (seg == 2) ? wv : wo;
        dst = (seg == 0) ? wqb : (seg == 1) ? wkb : (seg == 2) ? wvb : wob;
    }
    float4 v = *(const float4*)(src + off);
    dst[off + 0] = __float2bfloat16(v.x);
    dst[off + 1] = __float2bfloat16(v.y);
    dst[off + 2] = __float2bfloat16(v.z);
    dst[off + 3] = __float2bfloat16(v.w);
}

// Fused QKV projection: C_sec[m][n] = sum_k x[m][k] * Wsec[n][k], sec = blockIdx.x>>3.
// sec 0 -> Q' (RoPE * QSCALE), sec 1 -> K' (RoPE), sec 2 -> V'  (tiled layouts above).
__global__ __launch_bounds__(256) void qkv_gemm(
    const __hip_bfloat16* __restrict__ A,
    const __hip_bfloat16* __restrict__ Bq,
    const __hip_bfloat16* __restrict__ Bk,
    const __hip_bfloat16* __restrict__ Bv,
    __hip_bfloat16* __restrict__ Qb,
    __hip_bfloat16* __restrict__ Kb,
    __hip_bfloat16* __restrict__ Vtb)
{
    __shared__ __hip_bfloat16 As[128 * 32];
    __shared__ __hip_bfloat16 Bs[128 * 32];
    const int tid  = threadIdx.x;
    const int wave = tid >> 6;
    const int lane = tid & 63;
    const int quad = lane >> 4;
    const int l15  = lane & 15;
    const int sec  = blockIdx.x >> 3;                 // 0=Q 1=K 2=V
    const __hip_bfloat16* B = (sec == 0) ? Bq : (sec == 1) ? Bk : Bv;
    const int n0 = (blockIdx.x & 7) * 128;            // col base within section
    const int m0 = blockIdx.y * 128;
    const int wm = (wave & 1) * 64;
    const int wn = (wave >> 1) * 64;

    floatx4 acc[4][4] = {};

    for (int kt = 0; kt < DMODEL; kt += 32) {
        #pragma unroll
        for (int p = 0; p < 2; ++p) {
            int base = (p * 4 + wave) * 1024;
            int b    = base + lane * 16;
            int row  = b >> 6;
            int ke   = (b & 63) >> 1;
            load_lds16(A + (size_t)(m0 + row) * DMODEL + kt + ke, (char*)As + base);
            load_lds16(B + (size_t)(n0 + row) * DMODEL + kt + ke, (char*)Bs + base);
        }
        __syncthreads();
        short8 af[4], bf[4];
        #pragma unroll
        for (int i = 0; i < 4; ++i)
            af[i] = *(const short8*)(As + (wm + i * 16 + l15) * 32 + quad * 8);
        #pragma unroll
        for (int j = 0; j < 4; ++j)
            bf[j] = *(const short8*)(Bs + (wn + j * 16 + l15) * 32 + quad * 8);
        #pragma unroll
        for (int i = 0; i < 4; ++i)
            #pragma unroll
            for (int j = 0; j < 4; ++j)
                acc[i][j] = __builtin_amdgcn_mfma_f32_16x16x32_bf16(af[i], bf[j], acc[i][j], 0, 0, 0);
        __syncthreads();
    }

    // epilogue. C/D layout: col = lane&15, row = quad*4 + reg (m89/m91 verified)
    float ifreq[4];
    #pragma unroll
    for (int j = 0; j < 4; ++j) {
        int d = (j * 16 + l15) & 63;
        ifreq[j] = expf(-(float)(d & ~1) * (9.210340371976184f / 64.0f)); // theta^(-2i/64)
    }
    const float scale = (sec == 0) ? QSCALE : 1.0f;
    __hip_bfloat16* dst = (sec == 0) ? Qb : Kb;
    #pragma unroll
    for (int i = 0; i < 4; ++i) {
        int rowb = m0 + wm + i * 16 + quad * 4;
        #pragma unroll
        for (int j = 0; j < 4; ++j) {
            int col = n0 + wn + j * 16 + l15;   // section-local column
            int h   = col >> 6;
            int hd  = col & 63;
            if (sec == 2) {
                // V': [od][s>>3][d&15][s&7]; 4 consecutive s (same granule) -> 8B store
                union { short4_t v; __hip_bfloat16 b[4]; } pk;
                #pragma unroll
                for (int r = 0; r < 4; ++r) pk.b[r] = __float2bfloat16(acc[i][j][r]);
                int od = hd >> 4, lv = hd & 15;
                *(short4_t*)(Vtb + (size_t)h * 262144 +
                             (((od * 512 + (rowb >> 3)) * 16 + lv) << 3) + (rowb & 7)) = pk.v;
            } else {
                int g = hd >> 3, jj = hd & 7;
                #pragma unroll
                for (int r = 0; r < 4; ++r) {
                    int rr  = rowb + r;
                    float v = acc[i][j][r];
                    float ang = (float)rr * ifreq[j];
                    float sn, cs;
                    __sincosf(ang, &sn, &cs);
                    float pv  = __shfl_xor(v, 1);
                    float out = ((lane & 1) ? (pv * sn + v * cs)
                                            : (v * cs - pv * sn)) * scale;
                    dst[(size_t)h * 262144 +
                        ((((rr >> 4) * 8 + g) * 16 + (rr & 15)) << 3) + jj] = __float2bfloat16(out);
                }
            }
        }
    }
}

// One kv-tile (64 kv x 64 q) for one wave, R2-proven orientation.
// S_g = mfma(aq[g], kf[ni]): lane (quad,l15) reg r: q = g*16+quad*4+r, kv = ni*16+l15.
template<bool EDGE>
static __device__ __forceinline__ void attn_tile(
    int kt, int quad, int l15,
    const __hip_bfloat16* __restrict__ Kh, const __hip_bfloat16* __restrict__ Vh,
    const short8 aq[4][2], floatx4 o[4][4], float lp[4][4],
    __hip_bfloat16* __restrict__ PsW)   // 64-row x 68-col per-wave strip
{
    // drain LDS pipe: previous tile's ap reads complete before we overwrite the
    // strip (replaces the ordering R2's __syncthreads provided; ~free here).
    asm volatile("s_waitcnt lgkmcnt(0)" ::: "memory");

    short8 kf[4][2], vf[4][2];
    #pragma unroll
    for (int ni = 0; ni < 4; ++ni)
        #pragma unroll
        for (int dc = 0; dc < 2; ++dc)
            kf[ni][dc] = *(const short8*)(Kh + (size_t)(((((kt*4 + ni)*8 + dc*4 + quad)*16 + l15) << 3)));
    #pragma unroll
    for (int od = 0; od < 4; ++od)
        #pragma unroll
        for (int dc = 0; dc < 2; ++dc)
            vf[od][dc] = *(const short8*)(Vh + (size_t)((((od*512 + kt*8 + dc*4 + quad)*16 + l15) << 3)));

    // S + P for all 4 q-groups (each group has its own 16-row strip region)
    #pragma unroll
    for (int g = 0; g < 4; ++g) {
        floatx4 st[4];
        #pragma unroll
        for (int ni = 0; ni < 4; ++ni) {
            floatx4 z = {};
            floatx4 s = __builtin_amdgcn_mfma_f32_16x16x32_bf16(aq[g][0], kf[ni][0], z, 0, 0, 0);
            st[ni]    = __builtin_amdgcn_mfma_f32_16x16x32_bf16(aq[g][1], kf[ni][1], s, 0, 0, 0);
        }
        #pragma unroll
        for (int ni = 0; ni < 4; ++ni) {
            #pragma unroll
            for (int r = 0; r < 4; ++r) {
                float e = __builtin_amdgcn_exp2f(st[ni][r]);
                if (EDGE) {
                    if (ni * 16 + l15 > g * 16 + quad * 4 + r) e = 0.0f;  // kv_loc > q_loc
                }
                lp[g][r] += e;
                PsW[(g * 16 + quad * 4 + r) * 68 + ni * 16 + l15] = __float2bfloat16(e);
            }
        }
    }
    // P back as A-frags (R2's exact read pattern) + PV
    #pragma unroll
    for (int g = 0; g < 4; ++g) {
        short8 ap[2];
        #pragma unroll
        for (int dc = 0; dc < 2; ++dc) {
            const __hip_bfloat16* pp = PsW + (g * 16 + l15) * 68 + dc * 32 + quad * 8;
            short4_t p0 = *(const short4_t*)pp;
            short4_t p1 = *(const short4_t*)(pp + 4);
            short8 a;
            a[0] = p0[0]; a[1] = p0[1]; a[2] = p0[2]; a[3] = p0[3];
            a[4] = p1[0]; a[5] = p1[1]; a[6] = p1[2]; a[7] = p1[3];
            ap[dc] = a;
        }
        #pragma unroll
        for (int od = 0; od < 4; ++od) {
            o[g][od] = __builtin_amdgcn_mfma_f32_16x16x32_bf16(ap[0], vf[od][0], o[g][od], 0, 0, 0);
            o[g][od] = __builtin_amdgcn_mfma_f32_16x16x32_bf16(ap[1], vf[od][1], o[g][od], 0, 0, 0);
        }
    }
}

// Block = (head h = b&15, q64-tile u = 63-(b>>4), heavy-first). 4 independent waves
// split kv-tiles stride-4 (no barriers in the loop; max-free softmax => partials add).
__global__ __launch_bounds__(256) void attn_kernel(
    const __hip_bfloat16* __restrict__ Q,
    const __hip_bfloat16* __restrict__ Kp,
    const __hip_bfloat16* __restrict__ Vp,
    __hip_bfloat16* __restrict__ CTX)
{
    // Buf[w]: wave w's Ps strip during the kv loop; O-partial buffer in the merge
    __shared__ __hip_bfloat16 Buf[4][64 * 68];
    __shared__ float LPw[4][64];
    const int b  = blockIdx.x;
    const int h  = b & 15;
    const int u  = 63 - (b >> 4);
    const int tid  = threadIdx.x;
    const int wave = tid >> 6, lane = tid & 63;
    const int quad = lane >> 4, l15 = lane & 15;

    const __hip_bfloat16* Qh = Q  + (size_t)h * 262144;
    const __hip_bfloat16* Kh = Kp + (size_t)h * 262144;
    const __hip_bfloat16* Vh = Vp + (size_t)h * 262144;
    __hip_bfloat16* PsW = &Buf[wave][0];

    // Q A-frags for the 4 16-row groups of this q-tile (QSCALE*log2e folded in)
    short8 aq[4][2];
    #pragma unroll
    for (int g = 0; g < 4; ++g)
        #pragma unroll
        for (int dc = 0; dc < 2; ++dc)
            aq[g][dc] = *(const short8*)(Qh + (size_t)(((((u*4 + g)*8 + dc*4 + quad)*16 + l15) << 3)));

    floatx4 o[4][4] = {};
    float lp[4][4] = {};

    for (int kt = wave; kt < u; kt += 4)
        attn_tile<false>(kt, quad, l15, Kh, Vh, aq, o, lp, PsW);
    if ((u & 3) == wave)
        attn_tile<true>(u, quad, l15, Kh, Vh, aq, o, lp, PsW);

    // ---- merge: reduce lp across the 16-lane col group, dump partials, combine ----
    #pragma unroll
    for (int g = 0; g < 4; ++g)
        #pragma unroll
        for (int r = 0; r < 4; ++r) {
            float v = lp[g][r];
            v += __shfl_xor(v, 1);
            v += __shfl_xor(v, 2);
            v += __shfl_xor(v, 4);
            v += __shfl_xor(v, 8);
            lp[g][r] = v;
        }
    asm volatile("s_waitcnt lgkmcnt(0)" ::: "memory");  // last tile's ap reads done
    if (l15 == 0) {
        #pragma unroll
        for (int g = 0; g < 4; ++g)
            #pragma unroll
            for (int r = 0; r < 4; ++r)
                LPw[wave][g * 16 + quad * 4 + r] = lp[g][r];
    }
    #pragma unroll
    for (int g = 0; g < 4; ++g)
        #pragma unroll
        for (int od = 0; od < 4; ++od)
            #pragma unroll
            for (int r = 0; r < 4; ++r)
                Buf[wave][(g * 16 + quad * 4 + r) * 68 + od * 16 + l15] =
                    __float2bfloat16(o[g][od][r]);
    __syncthreads();

    // wave w normalizes + writes q-rows [w*16, w*16+16)
    #pragma unroll
    for (int r = 0; r < 4; ++r) {
        int q = wave * 16 + quad * 4 + r;
        float ls = LPw[0][q] + LPw[1][q] + LPw[2][q] + LPw[3][q];
        float rl = __frcp_rn(ls);
        #pragma unroll
        for (int od = 0; od < 4; ++od) {
            float s = 0.0f;
            #pragma unroll
            for (int sl = 0; sl < 4; ++sl)
                s += __bfloat162float(Buf[sl][q * 68 + od * 16 + l15]);
            CTX[(size_t)(u * 64 + q) * DMODEL + h * 64 + od * 16 + l15] =
                __float2bfloat16(s * rl);
        }
    }
}

// Out projection: C[m][n] = sum_k Cx[m][k] * Wo[n][k], fp32 out. 128x64 tiles.
__global__ __launch_bounds__(256) void out_gemm(
    const __hip_bfloat16* __restrict__ A,
    const __hip_bfloat16* __restrict__ B,
    float* __restrict__ C)
{
    __shared__ __hip_bfloat16 As[128 * 32];
    __shared__ __hip_bfloat16 Bs[64 * 32];
    const int tid  = threadIdx.x;
    const int wave = tid >> 6;
    const int lane = tid & 63;
    const int quad = lane >> 4;
    const int l15  = lane & 15;
    const int n0 = blockIdx.x * 64;
    const int m0 = blockIdx.y * 128;
    const int wm = (wave & 1) * 64;
    const int wn = (wave >> 1) * 32;

    floatx4 acc[4][2] = {};

    for (int kt = 0; kt < DMODEL; kt += 32) {
        #pragma unroll
        for (int p = 0; p < 3; ++p) {
            int id  = p * 4 + wave;            // 0..11
            if (id < 8) {
                int base = id * 1024;
                int b    = base + lane * 16;
                int row  = b >> 6;
                int ke   = (b & 63) >> 1;
                load_lds16(A + (size_t)(m0 + row) * DMODEL + kt + ke, (char*)As + base);
            } else {
                int base = (id - 8) * 1024;
                int b    = base + lane * 16;
                int row  = b >> 6;
                int ke   = (b & 63) >> 1;
                load_lds16(B + (size_t)(n0 + row) * DMODEL + kt + ke, (char*)Bs + base);
            }
        }
        __syncthreads();
        short8 af[4], bf[2];
        #pragma unroll
        for (int i = 0; i < 4; ++i)
            af[i] = *(const short8*)(As + (wm + i * 16 + l15) * 32 + quad * 8);
        #pragma unroll
        for (int j = 0; j < 2; ++j)
            bf[j] = *(const short8*)(Bs + (wn + j * 16 + l15) * 32 + quad * 8);
        #pragma unroll
        for (int i = 0; i < 4; ++i)
            #pragma unroll
            for (int j = 0; j < 2; ++j)
                acc[i][j] = __builtin_amdgcn_mfma_f32_16x16x32_bf16(af[i], bf[j], acc[i][j], 0, 0, 0);
        __syncthreads();
    }

    #pragma unroll
    for (int i = 0; i < 4; ++i) {
        int rowb = m0 + wm + i * 16 + quad * 4;
        #pragma unroll
        for (int j = 0; j < 2; ++j) {
            int col = n0 + wn + j * 16 + l15;
            #pragma unroll
            for (int r = 0; r < 4; ++r)
                C[(size_t)(rowb + r) * DMODEL + col] = acc[i][j][r];
        }
    }
}

extern "C" void kernel_launch(void* const* d_in, const int* in_sizes, int n_in,
                              void* d_out, int out_size, void* d_ws, size_t ws_size,
                              hipStream_t stream)
{
    const float* x  = (const float*)d_in[0];
    const float* Wq = (const float*)d_in[1];
    const float* Wk = (const float*)d_in[2];
    const float* Wv = (const float*)d_in[3];
    const float* Wo = (const float*)d_in[4];

    char* ws = (char*)d_ws;
    const size_t MB = 1024 * 1024;
    __hip_bfloat16* xb  = (__hip_bfloat16*)(ws);            //  8 MB
    __hip_bfloat16* wqb = (__hip_bfloat16*)(ws +  8 * MB);  //  2 MB
    __hip_bfloat16* wkb = (__hip_bfloat16*)(ws + 10 * MB);  //  2 MB
    __hip_bfloat16* wvb = (__hip_bfloat16*)(ws + 12 * MB);  //  2 MB
    __hip_bfloat16* wob = (__hip_bfloat16*)(ws + 14 * MB);  //  2 MB
    __hip_bfloat16* Qb  = (__hip_bfloat16*)(ws + 16 * MB);  //  8 MB  Q' tiled (*QSCALE)
    __hip_bfloat16* Kbf = (__hip_bfloat16*)(ws + 24 * MB);  //  8 MB  K' tiled
    __hip_bfloat16* Vtb = (__hip_bfloat16*)(ws + 32 * MB);  //  8 MB  V' tiled
    __hip_bfloat16* Cx  = (__hip_bfloat16*)(ws + 40 * MB);  //  8 MB  [s][1024]

    cvt_all_kernel<<<8192, 256, 0, stream>>>(x, Wq, Wk, Wv, Wo, xb, wqb, wkb, wvb, wob);

    qkv_gemm<<<dim3(24, 32), 256, 0, stream>>>(xb, wqb, wkb, wvb, Qb, Kbf, Vtb);

    attn_kernel<<<1024, 256, 0, stream>>>(Qb, Kbf, Vtb, Cx);

    out_gemm<<<dim3(16, 32), 256, 0, stream>>>(Cx, wob, (float*)d_out);
}

// Round 6
// 202.405 us; speedup vs baseline: 1.0946x; 1.0946x over previous
//
#include <hip/hip_runtime.h>
#include <hip/hip_bf16.h>
#include <math.h>

// MultiHeadSelfAttention: x[1,4096,1024] fp32, Wq/Wk/Wv/Wo[1024,1024] fp32 -> out fp32.
// R5: R4 skeleton (tiled layouts, barrier-free wave-split attn, end merge - all
// R4-verified) + transposed QK per-tile compute:
//   S^T = mfma(K_asA, Q_asB): lane reg r = P(kv = ni*16+quad*4+r, q = g*16+l15)
//   -> 4 consecutive kv per lane -> pack bf16x2 (v_add+v_perm, no software-RNE cvt)
//   -> ONE ds_write_b64 per ni (was 16 ds_write_b16), b64-pair reads back as A-frag.
// Per-g strips are DISJOINT (R3's strip-reuse same-wave WAR was the R3 bug; same-wave
// DS ordering is NOT guaranteed); cross-tile strip reuse guarded by tile-start
// s_waitcnt lgkmcnt(0) (R4-proven). Fast bit-cvt (add 0x8000, shift) replaces
// __float2bfloat16's software-RNE expansion everywhere on hot paths.
//
// Tiled layouts (per head, 256KB = 4096x64 bf16), R4-verified:
//   Q'/K'[t16 = s>>4][g8 = d>>3][l = s&15][j = d&7]   (granule = 8 bf16 = 16B)
//   V'  [od = d>>4][kg = s>>3][l = d&15][j = s&7]

#define S_LEN 4096
#define DMODEL 1024
#define NHEAD 16
// 0.125 (1/sqrt(64)) * log2(e): folded into Q so attn uses exp2 directly
#define QSCALE 0.1803368801111244f
#define PSTR 76   // P/merge strip stride (elems): <=2-way banks for b64 W/R, 8B-aligned rows

typedef __attribute__((ext_vector_type(8))) short short8;   // 8 bf16 = 4 VGPRs
typedef __attribute__((ext_vector_type(4))) short short4_t; // 4 bf16 = 2 VGPRs
typedef __attribute__((ext_vector_type(2))) unsigned int uint2_t;
typedef __attribute__((ext_vector_type(4))) float floatx4;  // MFMA C/D frag

static __device__ __forceinline__ void load_lds16(const void* g, void* l) {
    __builtin_amdgcn_global_load_lds((const __attribute__((address_space(1))) void*)g,
                                     (__attribute__((address_space(3))) void*)l, 16, 0, 0);
}

// round-half-up f32->bf16: 2 VALU (vs software-RNE ~6)
static __device__ __forceinline__ __hip_bfloat16 bf16_fast(float f) {
    unsigned int u = __builtin_bit_cast(unsigned int, f) + 0x8000u;
    unsigned short s = (unsigned short)(u >> 16);
    return __builtin_bit_cast(__hip_bfloat16, s);
}
// pack two f32 -> bf16x2 dword: 2 v_add + 1 v_perm
static __device__ __forceinline__ unsigned int pack_bf16x2(float a, float b) {
    unsigned int ua = __builtin_bit_cast(unsigned int, a) + 0x8000u;
    unsigned int ub = __builtin_bit_cast(unsigned int, b) + 0x8000u;
    return __builtin_amdgcn_perm(ub, ua, 0x07060302);  // {ua.hi16, ub.hi16}
}

// one fused launch for all 5 fp32->bf16 conversions
__global__ void cvt_all_kernel(const float* __restrict__ x,  const float* __restrict__ wq,
                               const float* __restrict__ wk, const float* __restrict__ wv,
                               const float* __restrict__ wo,
                               __hip_bfloat16* __restrict__ xb,  __hip_bfloat16* __restrict__ wqb,
                               __hip_bfloat16* __restrict__ wkb, __hip_bfloat16* __restrict__ wvb,
                               __hip_bfloat16* __restrict__ wob)
{
    const size_t NX = (size_t)S_LEN * DMODEL;   // 4M
    const size_t NW = (size_t)DMODEL * DMODEL;  // 1M
    size_t t = ((size_t)blockIdx.x * blockDim.x + threadIdx.x) * 4;
    const float* src; __hip_bfloat16* dst; size_t off;
    if (t < NX) { src = x; dst = xb; off = t; }
    else {
        size_t j = t - NX; int seg = (int)(j >> 20); off = j & (NW - 1);
        src = (seg == 0) ? wq : (seg == 1) ? wk : (seg == 2) ? wv : wo;
        dst = (seg == 0) ? wqb : (seg == 1) ? wkb : (seg == 2) ? wvb : wob;
    }
    float4 v = *(const float4*)(src + off);
    uint2_t w;
    w.x = pack_bf16x2(v.x, v.y);
    w.y = pack_bf16x2(v.z, v.w);
    *(uint2_t*)(dst + off) = w;
}

// Fused QKV projection: C_sec[m][n] = sum_k x[m][k] * Wsec[n][k], sec = blockIdx.x>>3.
// sec 0 -> Q' (RoPE * QSCALE), sec 1 -> K' (RoPE), sec 2 -> V'  (tiled layouts above).
__global__ __launch_bounds__(256) void qkv_gemm(
    const __hip_bfloat16* __restrict__ A,
    const __hip_bfloat16* __restrict__ Bq,
    const __hip_bfloat16* __restrict__ Bk,
    const __hip_bfloat16* __restrict__ Bv,
    __hip_bfloat16* __restrict__ Qb,
    __hip_bfloat16* __restrict__ Kb,
    __hip_bfloat16* __restrict__ Vtb)
{
    __shared__ __hip_bfloat16 As[128 * 32];
    __shared__ __hip_bfloat16 Bs[128 * 32];
    const int tid  = threadIdx.x;
    const int wave = tid >> 6;
    const int lane = tid & 63;
    const int quad = lane >> 4;
    const int l15  = lane & 15;
    const int sec  = blockIdx.x >> 3;                 // 0=Q 1=K 2=V
    const __hip_bfloat16* B = (sec == 0) ? Bq : (sec == 1) ? Bk : Bv;
    const int n0 = (blockIdx.x & 7) * 128;            // col base within section
    const int m0 = blockIdx.y * 128;
    const int wm = (wave & 1) * 64;
    const int wn = (wave >> 1) * 64;

    floatx4 acc[4][4] = {};

    for (int kt = 0; kt < DMODEL; kt += 32) {
        #pragma unroll
        for (int p = 0; p < 2; ++p) {
            int base = (p * 4 + wave) * 1024;
            int b    = base + lane * 16;
            int row  = b >> 6;
            int ke   = (b & 63) >> 1;
            load_lds16(A + (size_t)(m0 + row) * DMODEL + kt + ke, (char*)As + base);
            load_lds16(B + (size_t)(n0 + row) * DMODEL + kt + ke, (char*)Bs + base);
        }
        __syncthreads();
        short8 af[4], bf[4];
        #pragma unroll
        for (int i = 0; i < 4; ++i)
            af[i] = *(const short8*)(As + (wm + i * 16 + l15) * 32 + quad * 8);
        #pragma unroll
        for (int j = 0; j < 4; ++j)
            bf[j] = *(const short8*)(Bs + (wn + j * 16 + l15) * 32 + quad * 8);
        #pragma unroll
        for (int i = 0; i < 4; ++i)
            #pragma unroll
            for (int j = 0; j < 4; ++j)
                acc[i][j] = __builtin_amdgcn_mfma_f32_16x16x32_bf16(af[i], bf[j], acc[i][j], 0, 0, 0);
        __syncthreads();
    }

    // epilogue. C/D layout: col = lane&15, row = quad*4 + reg (m89/m91 verified)
    float ifreq[4];
    #pragma unroll
    for (int j = 0; j < 4; ++j) {
        int d = (j * 16 + l15) & 63;
        ifreq[j] = expf(-(float)(d & ~1) * (9.210340371976184f / 64.0f)); // theta^(-2i/64)
    }
    const float scale = (sec == 0) ? QSCALE : 1.0f;
    __hip_bfloat16* dst = (sec == 0) ? Qb : Kb;
    #pragma unroll
    for (int i = 0; i < 4; ++i) {
        int rowb = m0 + wm + i * 16 + quad * 4;
        #pragma unroll
        for (int j = 0; j < 4; ++j) {
            int col = n0 + wn + j * 16 + l15;   // section-local column
            int h   = col >> 6;
            int hd  = col & 63;
            if (sec == 2) {
                // V': [od][s>>3][d&15][s&7]; 4 consecutive s (same granule) -> 8B store
                uint2_t w;
                w.x = pack_bf16x2(acc[i][j][0], acc[i][j][1]);
                w.y = pack_bf16x2(acc[i][j][2], acc[i][j][3]);
                int od = hd >> 4, lv = hd & 15;
                *(uint2_t*)(Vtb + (size_t)h * 262144 +
                            (((od * 512 + (rowb >> 3)) * 16 + lv) << 3) + (rowb & 7)) = w;
            } else {
                int g = hd >> 3, jj = hd & 7;
                #pragma unroll
                for (int r = 0; r < 4; ++r) {
                    int rr  = rowb + r;
                    float v = acc[i][j][r];
                    float ang = (float)rr * ifreq[j];
                    float sn, cs;
                    __sincosf(ang, &sn, &cs);
                    float pv  = __shfl_xor(v, 1);
                    float out = ((lane & 1) ? (pv * sn + v * cs)
                                            : (v * cs - pv * sn)) * scale;
                    dst[(size_t)h * 262144 +
                        ((((rr >> 4) * 8 + g) * 16 + (rr & 15)) << 3) + jj] = bf16_fast(out);
                }
            }
        }
    }
}

// One kv-tile (64 kv x 64 q) for one wave, transposed orientation.
// S^T = mfma(kf as A, aq as B): lane (quad,l15) reg r = S[kv = ni*16+quad*4+r][q = g*16+l15]
// -> pack pairs -> one b64 write per ni into this g's DISJOINT strip rows (g*16+l15).
template<bool EDGE>
static __device__ __forceinline__ void attn_tile(
    int kt, int quad, int l15,
    const __hip_bfloat16* __restrict__ Kh, const __hip_bfloat16* __restrict__ Vh,
    const short8 aq[4][2], floatx4 o[4][4], float lp[4],
    __hip_bfloat16* __restrict__ PsW)   // 64 rows x PSTR per-wave strip
{
    // WAR guard: strips are reused across tiles; same-wave DS ordering is not
    // guaranteed (R3 lesson). Prior tile's ap reads must drain first.
    asm volatile("s_waitcnt lgkmcnt(0)" ::: "memory");

    short8 kf[4][2], vf[4][2];
    #pragma unroll
    for (int ni = 0; ni < 4; ++ni)
        #pragma unroll
        for (int dc = 0; dc < 2; ++dc)
            kf[ni][dc] = *(const short8*)(Kh + (size_t)(((((kt*4 + ni)*8 + dc*4 + quad)*16 + l15) << 3)));
    #pragma unroll
    for (int od = 0; od < 4; ++od)
        #pragma unroll
        for (int dc = 0; dc < 2; ++dc)
            vf[od][dc] = *(const short8*)(Vh + (size_t)((((od*512 + kt*8 + dc*4 + quad)*16 + l15) << 3)));

    #pragma unroll
    for (int g = 0; g < 4; ++g) {
        __hip_bfloat16* strip = PsW + (g * 16 + l15) * PSTR;  // this lane's q-row
        floatx4 st[4];
        #pragma unroll
        for (int ni = 0; ni < 4; ++ni) {
            floatx4 z = {};
            floatx4 s = __builtin_amdgcn_mfma_f32_16x16x32_bf16(kf[ni][0], aq[g][0], z, 0, 0, 0);
            st[ni]    = __builtin_amdgcn_mfma_f32_16x16x32_bf16(kf[ni][1], aq[g][1], s, 0, 0, 0);
        }
        #pragma unroll
        for (int ni = 0; ni < 4; ++ni) {
            float e[4];
            #pragma unroll
            for (int r = 0; r < 4; ++r) {
                float v = __builtin_amdgcn_exp2f(st[ni][r]);
                if (EDGE) {
                    if (ni * 16 + quad * 4 + r > g * 16 + l15) v = 0.0f;  // kv_loc > q_loc
                }
                e[r] = v;
            }
            lp[g] += (e[0] + e[1]) + (e[2] + e[3]);
            uint2_t w;
            w.x = pack_bf16x2(e[0], e[1]);
            w.y = pack_bf16x2(e[2], e[3]);
            // kv = ni*16 + quad*4 + {0..3}: contiguous, 8B-aligned -> one ds_write_b64
            *(short4_t*)(strip + ni * 16 + quad * 4) = __builtin_bit_cast(short4_t, w);
        }
        // P back as A-frag (R4-proven b64-pair read pattern): A[m=q=l15][k=kv]
        short8 ap[2];
        #pragma unroll
        for (int dc = 0; dc < 2; ++dc) {
            const __hip_bfloat16* pp = strip + dc * 32 + quad * 8;
            short4_t p0 = *(const short4_t*)pp;
            short4_t p1 = *(const short4_t*)(pp + 4);
            short8 a;
            a[0] = p0[0]; a[1] = p0[1]; a[2] = p0[2]; a[3] = p0[3];
            a[4] = p1[0]; a[5] = p1[1]; a[6] = p1[2]; a[7] = p1[3];
            ap[dc] = a;
        }
        #pragma unroll
        for (int od = 0; od < 4; ++od) {
            o[g][od] = __builtin_amdgcn_mfma_f32_16x16x32_bf16(ap[0], vf[od][0], o[g][od], 0, 0, 0);
            o[g][od] = __builtin_amdgcn_mfma_f32_16x16x32_bf16(ap[1], vf[od][1], o[g][od], 0, 0, 0);
        }
    }
}

// Block = (head h = b&15, q64-tile u = 63-(b>>4), heavy-first). 4 independent waves
// split kv-tiles stride-4 (no barriers in the loop; max-free softmax => partials add).
__global__ __launch_bounds__(256, 2) void attn_kernel(
    const __hip_bfloat16* __restrict__ Q,
    const __hip_bfloat16* __restrict__ Kp,
    const __hip_bfloat16* __restrict__ Vp,
    __hip_bfloat16* __restrict__ CTX)
{
    // Buf[w]: wave w's Ps strip during the kv loop; O-partial buffer in the merge
    __shared__ __hip_bfloat16 Buf[4][64 * PSTR];
    __shared__ float LPw[4][64];
    const int b  = blockIdx.x;
    const int h  = b & 15;
    const int u  = 63 - (b >> 4);
    const int tid  = threadIdx.x;
    const int wave = tid >> 6, lane = tid & 63;
    const int quad = lane >> 4, l15 = lane & 15;

    const __hip_bfloat16* Qh = Q  + (size_t)h * 262144;
    const __hip_bfloat16* Kh = Kp + (size_t)h * 262144;
    const __hip_bfloat16* Vh = Vp + (size_t)h * 262144;
    __hip_bfloat16* PsW = &Buf[wave][0];

    // Q A/B-frags for the 4 16-row groups of this q-tile (QSCALE*log2e folded in)
    short8 aq[4][2];
    #pragma unroll
    for (int g = 0; g < 4; ++g)
        #pragma unroll
        for (int dc = 0; dc < 2; ++dc)
            aq[g][dc] = *(const short8*)(Qh + (size_t)(((((u*4 + g)*8 + dc*4 + quad)*16 + l15) << 3)));

    floatx4 o[4][4] = {};
    float lp[4] = {};   // per-lane: sum over this wave's kv for q = g*16+l15

    for (int kt = wave; kt < u; kt += 4)
        attn_tile<false>(kt, quad, l15, Kh, Vh, aq, o, lp, PsW);
    if ((u & 3) == wave)
        attn_tile<true>(u, quad, l15, Kh, Vh, aq, o, lp, PsW);

    // ---- merge: reduce lp across quads (quads hold disjoint kv for same q) ----
    #pragma unroll
    for (int g = 0; g < 4; ++g) {
        float v = lp[g];
        v += __shfl_xor(v, 16);
        v += __shfl_xor(v, 32);
        lp[g] = v;
    }
    asm volatile("s_waitcnt lgkmcnt(0)" ::: "memory");  // last tile's ap reads done
    if (quad == 0) {
        #pragma unroll
        for (int g = 0; g < 4; ++g)
            LPw[wave][g * 16 + l15] = lp[g];
    }
    #pragma unroll
    for (int g = 0; g < 4; ++g)
        #pragma unroll
        for (int od = 0; od < 4; ++od)
            #pragma unroll
            for (int r = 0; r < 4; ++r)
                Buf[wave][(g * 16 + quad * 4 + r) * PSTR + od * 16 + l15] =
                    bf16_fast(o[g][od][r]);
    __syncthreads();

    // wave w normalizes + writes q-rows [w*16, w*16+16)
    #pragma unroll
    for (int r = 0; r < 4; ++r) {
        int q = wave * 16 + quad * 4 + r;
        float ls = LPw[0][q] + LPw[1][q] + LPw[2][q] + LPw[3][q];
        float rl = __frcp_rn(ls);
        #pragma unroll
        for (int od = 0; od < 4; ++od) {
            float s = 0.0f;
            #pragma unroll
            for (int sl = 0; sl < 4; ++sl)
                s += __bfloat162float(Buf[sl][q * PSTR + od * 16 + l15]);
            CTX[(size_t)(u * 64 + q) * DMODEL + h * 64 + od * 16 + l15] =
                bf16_fast(s * rl);
        }
    }
}

// Out projection: C[m][n] = sum_k Cx[m][k] * Wo[n][k], fp32 out. 128x64 tiles.
__global__ __launch_bounds__(256) void out_gemm(
    const __hip_bfloat16* __restrict__ A,
    const __hip_bfloat16* __restrict__ B,
    float* __restrict__ C)
{
    __shared__ __hip_bfloat16 As[128 * 32];
    __shared__ __hip_bfloat16 Bs[64 * 32];
    const int tid  = threadIdx.x;
    const int wave = tid >> 6;
    const int lane = tid & 63;
    const int quad = lane >> 4;
    const int l15  = lane & 15;
    const int n0 = blockIdx.x * 64;
    const int m0 = blockIdx.y * 128;
    const int wm = (wave & 1) * 64;
    const int wn = (wave >> 1) * 32;

    floatx4 acc[4][2] = {};

    for (int kt = 0; kt < DMODEL; kt += 32) {
        #pragma unroll
        for (int p = 0; p < 3; ++p) {
            int id  = p * 4 + wave;            // 0..11
            if (id < 8) {
                int base = id * 1024;
                int b    = base + lane * 16;
                int row  = b >> 6;
                int ke   = (b & 63) >> 1;
                load_lds16(A + (size_t)(m0 + row) * DMODEL + kt + ke, (char*)As + base);
            } else {
                int base = (id - 8) * 1024;
                int b    = base + lane * 16;
                int row  = b >> 6;
                int ke   = (b & 63) >> 1;
                load_lds16(B + (size_t)(n0 + row) * DMODEL + kt + ke, (char*)Bs + base);
            }
        }
        __syncthreads();
        short8 af[4], bf[2];
        #pragma unroll
        for (int i = 0; i < 4; ++i)
            af[i] = *(const short8*)(As + (wm + i * 16 + l15) * 32 + quad * 8);
        #pragma unroll
        for (int j = 0; j < 2; ++j)
            bf[j] = *(const short8*)(Bs + (wn + j * 16 + l15) * 32 + quad * 8);
        #pragma unroll
        for (int i = 0; i < 4; ++i)
            #pragma unroll
            for (int j = 0; j < 2; ++j)
                acc[i][j] = __builtin_amdgcn_mfma_f32_16x16x32_bf16(af[i], bf[j], acc[i][j], 0, 0, 0);
        __syncthreads();
    }

    #pragma unroll
    for (int i = 0; i < 4; ++i) {
        int rowb = m0 + wm + i * 16 + quad * 4;
        #pragma unroll
        for (int j = 0; j < 2; ++j) {
            int col = n0 + wn + j * 16 + l15;
            #pragma unroll
            for (int r = 0; r < 4; ++r)
                C[(size_t)(rowb + r) * DMODEL + col] = acc[i][j][r];
        }
    }
}

extern "C" void kernel_launch(void* const* d_in, const int* in_sizes, int n_in,
                              void* d_out, int out_size, void* d_ws, size_t ws_size,
                              hipStream_t stream)
{
    const float* x  = (const float*)d_in[0];
    const float* Wq = (const float*)d_in[1];
    const float* Wk = (const float*)d_in[2];
    const float* Wv = (const float*)d_in[3];
    const float* Wo = (const float*)d_in[4];

    char* ws = (char*)d_ws;
    const size_t MB = 1024 * 1024;
    __hip_bfloat16* xb  = (__hip_bfloat16*)(ws);            //  8 MB
    __hip_bfloat16* wqb = (__hip_bfloat16*)(ws +  8 * MB);  //  2 MB
    __hip_bfloat16* wkb = (__hip_bfloat16*)(ws + 10 * MB);  //  2 MB
    __hip_bfloat16* wvb = (__hip_bfloat16*)(ws + 12 * MB);  //  2 MB
    __hip_bfloat16* wob = (__hip_bfloat16*)(ws + 14 * MB);  //  2 MB
    __hip_bfloat16* Qb  = (__hip_bfloat16*)(ws + 16 * MB);  //  8 MB  Q' tiled (*QSCALE)
    __hip_bfloat16* Kbf = (__hip_bfloat16*)(ws + 24 * MB);  //  8 MB  K' tiled
    __hip_bfloat16* Vtb = (__hip_bfloat16*)(ws + 32 * MB);  //  8 MB  V' tiled
    __hip_bfloat16* Cx  = (__hip_bfloat16*)(ws + 40 * MB);  //  8 MB  [s][1024]

    cvt_all_kernel<<<8192, 256, 0, stream>>>(x, Wq, Wk, Wv, Wo, xb, wqb, wkb, wvb, wob);

    qkv_gemm<<<dim3(24, 32), 256, 0, stream>>>(xb, wqb, wkb, wvb, Qb, Kbf, Vtb);

    attn_kernel<<<1024, 256, 0, stream>>>(Qb, Kbf, Vtb, Cx);

    out_gemm<<<dim3(16, 32), 256, 0, stream>>>(Cx, wob, (float*)d_out);
}

// Round 7
// 189.302 us; speedup vs baseline: 1.1703x; 1.0692x over previous
//
#include <hip/hip_runtime.h>
#include <hip/hip_bf16.h>
#include <math.h>

// MultiHeadSelfAttention: x[1,4096,1024] fp32, Wq/Wk/Wv/Wo[1024,1024] fp32 -> out fp32.
// R6 = R5 (verified: tiled attn layouts, barrier-free wave-split attn, transposed-P
// b64 round-trip, fast bf16 cvt) + GEMM fixes:
//  - All GEMM-staged operands (xb, wq/wk/wv/wo, Cx) carry the R2-verified XOR swizzle:
//    granule g (8 bf16) of each 64-elem row-window stored at g^(row&7). Staging is a
//    verbatim copy -> LDS inherits it -> frag reads at (dc*4+quad)^(l15&7) are 2-way
//    (free) instead of ~8-way (qkv had 3.1e6 SQ_LDS_BANK_CONFLICT, out_gemm 1.57e6).
//  - BK 32 -> 64 (32KB LDS, 128B rows = exactly 32 banks): halves the per-block
//    barrier+vmcnt(0) drain count (the dominant per-iter cost at K=1024).
//
// Attn tiled layouts (per head, 256KB), R4-verified, unswizzled (global->reg loads):
//   Q'/K'[t16 = s>>4][g8 = d>>3][l = s&15][j = d&7]   (granule = 8 bf16 = 16B)
//   V'  [od = d>>4][kg = s>>3][l = d&15][j = s&7]

#define S_LEN 4096
#define DMODEL 1024
#define NHEAD 16
// 0.125 (1/sqrt(64)) * log2(e): folded into Q so attn uses exp2 directly
#define QSCALE 0.1803368801111244f
#define PSTR 76   // attn P/merge strip stride

typedef __attribute__((ext_vector_type(8))) short short8;   // 8 bf16 = 4 VGPRs
typedef __attribute__((ext_vector_type(4))) short short4_t; // 4 bf16 = 2 VGPRs
typedef __attribute__((ext_vector_type(2))) unsigned int uint2_t;
typedef __attribute__((ext_vector_type(4))) unsigned int uint4_t;
typedef __attribute__((ext_vector_type(4))) float floatx4;  // MFMA C/D frag

static __device__ __forceinline__ void load_lds16(const void* g, void* l) {
    __builtin_amdgcn_global_load_lds((const __attribute__((address_space(1))) void*)g,
                                     (__attribute__((address_space(3))) void*)l, 16, 0, 0);
}

// round-half-up f32->bf16: 2 VALU
static __device__ __forceinline__ __hip_bfloat16 bf16_fast(float f) {
    unsigned int u = __builtin_bit_cast(unsigned int, f) + 0x8000u;
    unsigned short s = (unsigned short)(u >> 16);
    return __builtin_bit_cast(__hip_bfloat16, s);
}
// pack two f32 -> bf16x2 dword: 2 v_add + 1 v_perm
static __device__ __forceinline__ unsigned int pack_bf16x2(float a, float b) {
    unsigned int ua = __builtin_bit_cast(unsigned int, a) + 0x8000u;
    unsigned int ub = __builtin_bit_cast(unsigned int, b) + 0x8000u;
    return __builtin_amdgcn_perm(ub, ua, 0x07060302);  // {ua.hi16, ub.hi16}
}

// fp32->bf16 for all 5 tensors, emitting the GEMM-staging swizzle:
// granule g = (k>>3)&7 of each 64-elem window stored at g^(row&7).
__global__ void cvt_all_kernel(const float* __restrict__ x,  const float* __restrict__ wq,
                               const float* __restrict__ wk, const float* __restrict__ wv,
                               const float* __restrict__ wo,
                               __hip_bfloat16* __restrict__ xb,  __hip_bfloat16* __restrict__ wqb,
                               __hip_bfloat16* __restrict__ wkb, __hip_bfloat16* __restrict__ wvb,
                               __hip_bfloat16* __restrict__ wob)
{
    const size_t NX = (size_t)S_LEN * DMODEL;   // 4M
    const size_t NW = (size_t)DMODEL * DMODEL;  // 1M
    size_t t = ((size_t)blockIdx.x * blockDim.x + threadIdx.x) * 8;  // one granule
    const float* src; __hip_bfloat16* dst; size_t off;
    if (t < NX) { src = x; dst = xb; off = t; }
    else {
        size_t j = t - NX; int seg = (int)(j >> 20); off = j & (NW - 1);
        src = (seg == 0) ? wq : (seg == 1) ? wk : (seg == 2) ? wv : wo;
        dst = (seg == 0) ? wqb : (seg == 1) ? wkb : (seg == 2) ? wvb : wob;
    }
    int row = (int)(off >> 10);
    int k   = (int)(off & 1023);
    int gp  = (((k >> 3) ^ row) & 7);
    size_t doff = (off & ~(size_t)1023) + (size_t)((k & ~63) + (gp << 3));
    float4 v0 = *(const float4*)(src + off);
    float4 v1 = *(const float4*)(src + off + 4);
    uint4_t w;
    w.x = pack_bf16x2(v0.x, v0.y);
    w.y = pack_bf16x2(v0.z, v0.w);
    w.z = pack_bf16x2(v1.x, v1.y);
    w.w = pack_bf16x2(v1.z, v1.w);
    *(uint4_t*)(dst + doff) = w;
}

// Fused QKV projection: C_sec[m][n] = sum_k x[m][k] * Wsec[n][k], sec = blockIdx.x>>3.
// Inputs swizzled (see cvt); BK=64; frag reads swizzle-corrected (2-way free banks).
// sec 0 -> Q' (RoPE * QSCALE), sec 1 -> K' (RoPE), sec 2 -> V'  (attn tiled layouts).
__global__ __launch_bounds__(256) void qkv_gemm(
    const __hip_bfloat16* __restrict__ A,
    const __hip_bfloat16* __restrict__ Bq,
    const __hip_bfloat16* __restrict__ Bk,
    const __hip_bfloat16* __restrict__ Bv,
    __hip_bfloat16* __restrict__ Qb,
    __hip_bfloat16* __restrict__ Kb,
    __hip_bfloat16* __restrict__ Vtb)
{
    __shared__ __hip_bfloat16 As[128 * 64];
    __shared__ __hip_bfloat16 Bs[128 * 64];
    const int tid  = threadIdx.x;
    const int wave = tid >> 6;
    const int lane = tid & 63;
    const int quad = lane >> 4;
    const int l15  = lane & 15;
    const int k7   = l15 & 7;
    const int sec  = blockIdx.x >> 3;                 // 0=Q 1=K 2=V
    const __hip_bfloat16* B = (sec == 0) ? Bq : (sec == 1) ? Bk : Bv;
    const int n0 = (blockIdx.x & 7) * 128;            // col base within section
    const int m0 = blockIdx.y * 128;
    const int wm = (wave & 1) * 64;
    const int wn = (wave >> 1) * 64;

    floatx4 acc[4][4] = {};

    for (int kt = 0; kt < DMODEL; kt += 64) {
        // 32 x 1KB chunks (As 16, Bs 16), 8 per wave; verbatim copy of the
        // pre-swizzled 128B row-windows.
        #pragma unroll
        for (int p = 0; p < 8; ++p) {
            int id  = p * 4 + wave;            // 0..31
            int cb  = (id & 15) * 1024;
            int bb  = cb + lane * 16;
            int row = bb >> 7;                  // 128B per row
            int ce  = (bb & 127) >> 1;
            if (id < 16)
                load_lds16(A + (size_t)(m0 + row) * DMODEL + kt + ce, (char*)As + cb);
            else
                load_lds16(B + (size_t)(n0 + row) * DMODEL + kt + ce, (char*)Bs + cb);
        }
        __syncthreads();
        #pragma unroll
        for (int dc = 0; dc < 2; ++dc) {
            short8 af[4], bf[4];
            #pragma unroll
            for (int i = 0; i < 4; ++i)
                af[i] = *(const short8*)(As + (wm + i * 16 + l15) * 64 + (((dc * 4 + quad) ^ k7) << 3));
            #pragma unroll
            for (int j = 0; j < 4; ++j)
                bf[j] = *(const short8*)(Bs + (wn + j * 16 + l15) * 64 + (((dc * 4 + quad) ^ k7) << 3));
            #pragma unroll
            for (int i = 0; i < 4; ++i)
                #pragma unroll
                for (int j = 0; j < 4; ++j)
                    acc[i][j] = __builtin_amdgcn_mfma_f32_16x16x32_bf16(af[i], bf[j], acc[i][j], 0, 0, 0);
        }
        __syncthreads();
    }

    // epilogue. C/D layout: col = lane&15, row = quad*4 + reg (m89/m91 verified)
    float ifreq[4];
    #pragma unroll
    for (int j = 0; j < 4; ++j) {
        int d = (j * 16 + l15) & 63;
        ifreq[j] = expf(-(float)(d & ~1) * (9.210340371976184f / 64.0f)); // theta^(-2i/64)
    }
    const float scale = (sec == 0) ? QSCALE : 1.0f;
    __hip_bfloat16* dst = (sec == 0) ? Qb : Kb;
    #pragma unroll
    for (int i = 0; i < 4; ++i) {
        int rowb = m0 + wm + i * 16 + quad * 4;
        #pragma unroll
        for (int j = 0; j < 4; ++j) {
            int col = n0 + wn + j * 16 + l15;   // section-local column
            int h   = col >> 6;
            int hd  = col & 63;
            if (sec == 2) {
                // V': [od][s>>3][d&15][s&7]; 4 consecutive s (same granule) -> 8B store
                uint2_t w;
                w.x = pack_bf16x2(acc[i][j][0], acc[i][j][1]);
                w.y = pack_bf16x2(acc[i][j][2], acc[i][j][3]);
                int od = hd >> 4, lv = hd & 15;
                *(uint2_t*)(Vtb + (size_t)h * 262144 +
                            (((od * 512 + (rowb >> 3)) * 16 + lv) << 3) + (rowb & 7)) = w;
            } else {
                int g = hd >> 3, jj = hd & 7;
                #pragma unroll
                for (int r = 0; r < 4; ++r) {
                    int rr  = rowb + r;
                    float v = acc[i][j][r];
                    float ang = (float)rr * ifreq[j];
                    float sn, cs;
                    __sincosf(ang, &sn, &cs);
                    float pv  = __shfl_xor(v, 1);
                    float out = ((lane & 1) ? (pv * sn + v * cs)
                                            : (v * cs - pv * sn)) * scale;
                    dst[(size_t)h * 262144 +
                        ((((rr >> 4) * 8 + g) * 16 + (rr & 15)) << 3) + jj] = bf16_fast(out);
                }
            }
        }
    }
}

// One kv-tile (64 kv x 64 q) for one wave, transposed orientation (R5-verified).
template<bool EDGE>
static __device__ __forceinline__ void attn_tile(
    int kt, int quad, int l15,
    const __hip_bfloat16* __restrict__ Kh, const __hip_bfloat16* __restrict__ Vh,
    const short8 aq[4][2], floatx4 o[4][4], float lp[4],
    __hip_bfloat16* __restrict__ PsW)   // 64 rows x PSTR per-wave strip
{
    // WAR guard: strips reused across tiles; same-wave DS ordering is NOT
    // guaranteed (R3 lesson). Prior tile's ap reads must drain first.
    asm volatile("s_waitcnt lgkmcnt(0)" ::: "memory");

    short8 kf[4][2], vf[4][2];
    #pragma unroll
    for (int ni = 0; ni < 4; ++ni)
        #pragma unroll
        for (int dc = 0; dc < 2; ++dc)
            kf[ni][dc] = *(const short8*)(Kh + (size_t)(((((kt*4 + ni)*8 + dc*4 + quad)*16 + l15) << 3)));
    #pragma unroll
    for (int od = 0; od < 4; ++od)
        #pragma unroll
        for (int dc = 0; dc < 2; ++dc)
            vf[od][dc] = *(const short8*)(Vh + (size_t)((((od*512 + kt*8 + dc*4 + quad)*16 + l15) << 3)));

    #pragma unroll
    for (int g = 0; g < 4; ++g) {
        __hip_bfloat16* strip = PsW + (g * 16 + l15) * PSTR;  // this lane's q-row
        floatx4 st[4];
        #pragma unroll
        for (int ni = 0; ni < 4; ++ni) {
            floatx4 z = {};
            floatx4 s = __builtin_amdgcn_mfma_f32_16x16x32_bf16(kf[ni][0], aq[g][0], z, 0, 0, 0);
            st[ni]    = __builtin_amdgcn_mfma_f32_16x16x32_bf16(kf[ni][1], aq[g][1], s, 0, 0, 0);
        }
        #pragma unroll
        for (int ni = 0; ni < 4; ++ni) {
            float e[4];
            #pragma unroll
            for (int r = 0; r < 4; ++r) {
                float v = __builtin_amdgcn_exp2f(st[ni][r]);
                if (EDGE) {
                    if (ni * 16 + quad * 4 + r > g * 16 + l15) v = 0.0f;  // kv_loc > q_loc
                }
                e[r] = v;
            }
            lp[g] += (e[0] + e[1]) + (e[2] + e[3]);
            uint2_t w;
            w.x = pack_bf16x2(e[0], e[1]);
            w.y = pack_bf16x2(e[2], e[3]);
            *(short4_t*)(strip + ni * 16 + quad * 4) = __builtin_bit_cast(short4_t, w);
        }
        short8 ap[2];
        #pragma unroll
        for (int dc = 0; dc < 2; ++dc) {
            const __hip_bfloat16* pp = strip + dc * 32 + quad * 8;
            short4_t p0 = *(const short4_t*)pp;
            short4_t p1 = *(const short4_t*)(pp + 4);
            short8 a;
            a[0] = p0[0]; a[1] = p0[1]; a[2] = p0[2]; a[3] = p0[3];
            a[4] = p1[0]; a[5] = p1[1]; a[6] = p1[2]; a[7] = p1[3];
            ap[dc] = a;
        }
        #pragma unroll
        for (int od = 0; od < 4; ++od) {
            o[g][od] = __builtin_amdgcn_mfma_f32_16x16x32_bf16(ap[0], vf[od][0], o[g][od], 0, 0, 0);
            o[g][od] = __builtin_amdgcn_mfma_f32_16x16x32_bf16(ap[1], vf[od][1], o[g][od], 0, 0, 0);
        }
    }
}

// Block = (head h = b&15, q64-tile u = 63-(b>>4), heavy-first). 4 independent waves
// split kv-tiles stride-4 (no barriers in the loop; max-free softmax => partials add).
// CTX written with the staging swizzle (consumed by out_gemm's verbatim staging).
__global__ __launch_bounds__(256, 2) void attn_kernel(
    const __hip_bfloat16* __restrict__ Q,
    const __hip_bfloat16* __restrict__ Kp,
    const __hip_bfloat16* __restrict__ Vp,
    __hip_bfloat16* __restrict__ CTX)
{
    __shared__ __hip_bfloat16 Buf[4][64 * PSTR];
    __shared__ float LPw[4][64];
    const int b  = blockIdx.x;
    const int h  = b & 15;
    const int u  = 63 - (b >> 4);
    const int tid  = threadIdx.x;
    const int wave = tid >> 6, lane = tid & 63;
    const int quad = lane >> 4, l15 = lane & 15;

    const __hip_bfloat16* Qh = Q  + (size_t)h * 262144;
    const __hip_bfloat16* Kh = Kp + (size_t)h * 262144;
    const __hip_bfloat16* Vh = Vp + (size_t)h * 262144;
    __hip_bfloat16* PsW = &Buf[wave][0];

    short8 aq[4][2];
    #pragma unroll
    for (int g = 0; g < 4; ++g)
        #pragma unroll
        for (int dc = 0; dc < 2; ++dc)
            aq[g][dc] = *(const short8*)(Qh + (size_t)(((((u*4 + g)*8 + dc*4 + quad)*16 + l15) << 3)));

    floatx4 o[4][4] = {};
    float lp[4] = {};

    for (int kt = wave; kt < u; kt += 4)
        attn_tile<false>(kt, quad, l15, Kh, Vh, aq, o, lp, PsW);
    if ((u & 3) == wave)
        attn_tile<true>(u, quad, l15, Kh, Vh, aq, o, lp, PsW);

    // ---- merge ----
    #pragma unroll
    for (int g = 0; g < 4; ++g) {
        float v = lp[g];
        v += __shfl_xor(v, 16);
        v += __shfl_xor(v, 32);
        lp[g] = v;
    }
    asm volatile("s_waitcnt lgkmcnt(0)" ::: "memory");
    if (quad == 0) {
        #pragma unroll
        for (int g = 0; g < 4; ++g)
            LPw[wave][g * 16 + l15] = lp[g];
    }
    #pragma unroll
    for (int g = 0; g < 4; ++g)
        #pragma unroll
        for (int od = 0; od < 4; ++od)
            #pragma unroll
            for (int r = 0; r < 4; ++r)
                Buf[wave][(g * 16 + quad * 4 + r) * PSTR + od * 16 + l15] =
                    bf16_fast(o[g][od][r]);
    __syncthreads();

    // wave w normalizes + writes q-rows [w*16, w*16+16), swizzled for out_gemm staging
    #pragma unroll
    for (int r = 0; r < 4; ++r) {
        int q   = wave * 16 + quad * 4 + r;
        int row = u * 64 + q;
        float ls = LPw[0][q] + LPw[1][q] + LPw[2][q] + LPw[3][q];
        float rl = __frcp_rn(ls);
        #pragma unroll
        for (int od = 0; od < 4; ++od) {
            float s = 0.0f;
            #pragma unroll
            for (int sl = 0; sl < 4; ++sl)
                s += __bfloat162float(Buf[sl][q * PSTR + od * 16 + l15]);
            int cidx = od * 16 + l15;                       // 0..63 in head window
            int gp   = (((cidx >> 3) ^ row) & 7);
            CTX[(size_t)row * DMODEL + h * 64 + (gp << 3) + (cidx & 7)] =
                bf16_fast(s * rl);
        }
    }
}

// Out projection: C[m][n] = sum_k Cx[m][k] * Wo[n][k], fp32 out. 128x64 tiles, BK=64,
// swizzled inputs (Cx from attn, wob from cvt).
__global__ __launch_bounds__(256) void out_gemm(
    const __hip_bfloat16* __restrict__ A,
    const __hip_bfloat16* __restrict__ B,
    float* __restrict__ C)
{
    __shared__ __hip_bfloat16 As[128 * 64];
    __shared__ __hip_bfloat16 Bs[64 * 64];
    const int tid  = threadIdx.x;
    const int wave = tid >> 6;
    const int lane = tid & 63;
    const int quad = lane >> 4;
    const int l15  = lane & 15;
    const int k7   = l15 & 7;
    const int n0 = blockIdx.x * 64;
    const int m0 = blockIdx.y * 128;
    const int wm = (wave & 1) * 64;
    const int wn = (wave >> 1) * 32;

    floatx4 acc[4][2] = {};

    for (int kt = 0; kt < DMODEL; kt += 64) {
        // 24 x 1KB chunks (As 16, Bs 8), 6 per wave
        #pragma unroll
        for (int p = 0; p < 6; ++p) {
            int id  = p * 4 + wave;            // 0..23
            if (id < 16) {
                int cb  = id * 1024;
                int bb  = cb + lane * 16;
                int row = bb >> 7;
                int ce  = (bb & 127) >> 1;
                load_lds16(A + (size_t)(m0 + row) * DMODEL + kt + ce, (char*)As + cb);
            } else {
                int cb  = (id - 16) * 1024;
                int bb  = cb + lane * 16;
                int row = bb >> 7;
                int ce  = (bb & 127) >> 1;
                load_lds16(B + (size_t)(n0 + row) * DMODEL + kt + ce, (char*)Bs + cb);
            }
        }
        __syncthreads();
        #pragma unroll
        for (int dc = 0; dc < 2; ++dc) {
            short8 af[4], bf[2];
            #pragma unroll
            for (int i = 0; i < 4; ++i)
                af[i] = *(const short8*)(As + (wm + i * 16 + l15) * 64 + (((dc * 4 + quad) ^ k7) << 3));
            #pragma unroll
            for (int j = 0; j < 2; ++j)
                bf[j] = *(const short8*)(Bs + (wn + j * 16 + l15) * 64 + (((dc * 4 + quad) ^ k7) << 3));
            #pragma unroll
            for (int i = 0; i < 4; ++i)
                #pragma unroll
                for (int j = 0; j < 2; ++j)
                    acc[i][j] = __builtin_amdgcn_mfma_f32_16x16x32_bf16(af[i], bf[j], acc[i][j], 0, 0, 0);
        }
        __syncthreads();
    }

    #pragma unroll
    for (int i = 0; i < 4; ++i) {
        int rowb = m0 + wm + i * 16 + quad * 4;
        #pragma unroll
        for (int j = 0; j < 2; ++j) {
            int col = n0 + wn + j * 16 + l15;
            #pragma unroll
            for (int r = 0; r < 4; ++r)
                C[(size_t)(rowb + r) * DMODEL + col] = acc[i][j][r];
        }
    }
}

extern "C" void kernel_launch(void* const* d_in, const int* in_sizes, int n_in,
                              void* d_out, int out_size, void* d_ws, size_t ws_size,
                              hipStream_t stream)
{
    const float* x  = (const float*)d_in[0];
    const float* Wq = (const float*)d_in[1];
    const float* Wk = (const float*)d_in[2];
    const float* Wv = (const float*)d_in[3];
    const float* Wo = (const float*)d_in[4];

    char* ws = (char*)d_ws;
    const size_t MB = 1024 * 1024;
    __hip_bfloat16* xb  = (__hip_bfloat16*)(ws);            //  8 MB (swizzled)
    __hip_bfloat16* wqb = (__hip_bfloat16*)(ws +  8 * MB);  //  2 MB (swizzled)
    __hip_bfloat16* wkb = (__hip_bfloat16*)(ws + 10 * MB);  //  2 MB (swizzled)
    __hip_bfloat16* wvb = (__hip_bfloat16*)(ws + 12 * MB);  //  2 MB (swizzled)
    __hip_bfloat16* wob = (__hip_bfloat16*)(ws + 14 * MB);  //  2 MB (swizzled)
    __hip_bfloat16* Qb  = (__hip_bfloat16*)(ws + 16 * MB);  //  8 MB  Q' tiled (*QSCALE)
    __hip_bfloat16* Kbf = (__hip_bfloat16*)(ws + 24 * MB);  //  8 MB  K' tiled
    __hip_bfloat16* Vtb = (__hip_bfloat16*)(ws + 32 * MB);  //  8 MB  V' tiled
    __hip_bfloat16* Cx  = (__hip_bfloat16*)(ws + 40 * MB);  //  8 MB  [s][1024] (swizzled)

    cvt_all_kernel<<<4096, 256, 0, stream>>>(x, Wq, Wk, Wv, Wo, xb, wqb, wkb, wvb, wob);

    qkv_gemm<<<dim3(24, 32), 256, 0, stream>>>(xb, wqb, wkb, wvb, Qb, Kbf, Vtb);

    attn_kernel<<<1024, 256, 0, stream>>>(Qb, Kbf, Vtb, Cx);

    out_gemm<<<dim3(16, 32), 256, 0, stream>>>(Cx, wob, (float*)d_out);
}